// Round 5
// baseline (570.815 us; speedup 1.0000x reference)
//
#include <hip/hip_runtime.h>

// GCN: out = A*(relu(A*(X*W1)+b1)*W2)+b2, A sparse COO, sorted row[].
// N=100000, E=3200000, IN=256, HID=256, OUT=64.
// Pipeline:
//   C1 = bf16(X)@W1 (MFMA, BM=64 BN=256, X read once)    -> bf16
//   Q1,s1 = rowquant_int8(C1)
//   ew = {col, vals*s1[col]}  (edge prep)
//   H  = relu(A@(Q1 deq)+b1)  via ew                      -> bf16 (overlays C1)
//   hw2 = H@W2 (MFMA)                                     -> bf16
//   Q2,s2 = rowquant_int8(hw2); ew = {col, vals*s2[col]}
//   out = A@(Q2 deq)+b2                                   -> fp32

constexpr int IN_SIZE = 256;
constexpr int HID = 256;
constexpr int OUTF = 64;

typedef __bf16 bf16x8 __attribute__((ext_vector_type(8)));
typedef float f32x4 __attribute__((ext_vector_type(4)));

__device__ __forceinline__ ushort f2b(float f) {
    uint u = __float_as_uint(f);
    uint r = (u + 0x7fffu + ((u >> 16) & 1u)) >> 16;   // RNE
    return (ushort)r;
}
__device__ __forceinline__ float b2f(ushort h) {
    return __uint_as_float(((uint)h) << 16);
}

// ---------------------------------------------------------------------------
__global__ void build_rowptr(const int* __restrict__ row, int* __restrict__ rp,
                             int n, int E) {
    int i = blockIdx.x * blockDim.x + threadIdx.x;
    if (i > n) return;
    int lo = 0, hi = E;
    while (lo < hi) {
        int mid = (lo + hi) >> 1;
        if (row[mid] < i) lo = mid + 1; else hi = mid;
    }
    rp[i] = lo;
}

// W [K,N] fp32 -> Wt [N,K] bf16
__global__ void transpose_cast(const float* __restrict__ in, ushort* __restrict__ out,
                               int K, int N) {
    int n = blockIdx.x;
    int k = threadIdx.x;
    if (k < K) out[(size_t)n * K + k] = f2b(in[(size_t)k * N + n]);
}

// ew[e] = {col[e], vals[e] * s[col[e]]}
__global__ void prep_edges(const float* __restrict__ vals, const int* __restrict__ col,
                           const float* __restrict__ s, int2* __restrict__ ew, int E) {
    int e = blockIdx.x * 256 + threadIdx.x;
    if (e >= E) return;
    int c = col[e];
    float w = vals[e] * s[c];
    ew[e] = make_int2(c, __float_as_int(w));
}

// ---------------------------------------------------------------------------
// GEMM1: C[M,256] = bf16(A_f32[M,256]) * Bt[256,256]^T. BM=64, BN=256, BK=32.
// 4 waves, each wave: 64 rows x 64 cols = acc[4][4]; 16 mfma 16x16x32/k-step.
__global__ __launch_bounds__(256)
void gemm1_cast(const float* __restrict__ A, const ushort* __restrict__ Bt,
                ushort* __restrict__ C, int M) {
    constexpr int K = 256;
    __shared__ ushort As[64 * 40];
    __shared__ ushort Bs[256 * 40];
    const int tid = threadIdx.x;
    const int wave = tid >> 6, lane = tid & 63;
    const int quad = lane >> 4, l = lane & 15;
    const int m0 = blockIdx.x * 64;

    // A staging: row ar=tid>>2 (0..63), 8 floats at ak=(tid&3)*8
    const int ar = tid >> 2;
    const int ak = (tid & 3) * 8;
    const size_t aoff = (size_t)min(m0 + ar, M - 1) * K + ak;
    // B staging: rows bn, bn+64, bn+128, bn+192; 8 elems at bkp
    const int bn = tid >> 2;
    const int bkp = (tid & 3) * 8;

    f32x4 acc[4][4] = {};

    for (int k0 = 0; k0 < K; k0 += 32) {
        float4 a0 = *(const float4*)(A + aoff + k0);
        float4 a1 = *(const float4*)(A + aoff + k0 + 4);
        uint4 bv[4];
#pragma unroll
        for (int j = 0; j < 4; ++j)
            bv[j] = *(const uint4*)(Bt + (size_t)(bn + 64 * j) * K + k0 + bkp);
        uint4 pa;
        pa.x = (uint)f2b(a0.x) | ((uint)f2b(a0.y) << 16);
        pa.y = (uint)f2b(a0.z) | ((uint)f2b(a0.w) << 16);
        pa.z = (uint)f2b(a1.x) | ((uint)f2b(a1.y) << 16);
        pa.w = (uint)f2b(a1.z) | ((uint)f2b(a1.w) << 16);
        __syncthreads();
        *(uint4*)&As[ar * 40 + ak] = pa;
#pragma unroll
        for (int j = 0; j < 4; ++j)
            *(uint4*)&Bs[(bn + 64 * j) * 40 + bkp] = bv[j];
        __syncthreads();

        bf16x8 af[4], bfr[4];
#pragma unroll
        for (int mt = 0; mt < 4; ++mt)
            af[mt] = *(const bf16x8*)&As[(mt * 16 + l) * 40 + quad * 8];
#pragma unroll
        for (int nt = 0; nt < 4; ++nt)
            bfr[nt] = *(const bf16x8*)&Bs[(wave * 64 + nt * 16 + l) * 40 + quad * 8];
#pragma unroll
        for (int mt = 0; mt < 4; ++mt)
#pragma unroll
            for (int nt = 0; nt < 4; ++nt)
                acc[mt][nt] = __builtin_amdgcn_mfma_f32_16x16x32_bf16(
                    af[mt], bfr[nt], acc[mt][nt], 0, 0, 0);
    }

#pragma unroll
    for (int mt = 0; mt < 4; ++mt)
#pragma unroll
        for (int nt = 0; nt < 4; ++nt)
#pragma unroll
            for (int reg = 0; reg < 4; ++reg) {
                int r = m0 + mt * 16 + quad * 4 + reg;
                int c = wave * 64 + nt * 16 + l;
                if (r < M) C[(size_t)r * 256 + c] = f2b(acc[mt][nt][reg]);
            }
}

// ---------------------------------------------------------------------------
// bf16 MFMA GEMM: C[M,N] = A[M,K] * Bt[N,K]^T. BM=128, BN=64, BK=32.
__global__ __launch_bounds__(256, 4)
void gemm_bf16(const ushort* __restrict__ A, const ushort* __restrict__ Bt,
               ushort* __restrict__ C, int M, int N, int K) {
    __shared__ ushort As[128 * 40];
    __shared__ ushort Bs[64 * 40];
    const int tid = threadIdx.x;
    const int wave = tid >> 6, lane = tid & 63;
    const int quad = lane >> 4, l = lane & 15;
    const int wr = wave >> 1, wc = wave & 1;
    const int m0 = blockIdx.x * 128, n0 = blockIdx.y * 64;

    const int crow = tid >> 2;
    const int cpart = (tid & 3) * 8;
    const size_t aoff0 = (size_t)min(m0 + crow, M - 1) * K + cpart;
    const size_t aoff1 = (size_t)min(m0 + crow + 64, M - 1) * K + cpart;
    const size_t boff  = (size_t)(n0 + crow) * K + cpart;

    f32x4 acc[4][2] = {};

    for (int k0 = 0; k0 < K; k0 += 32) {
        uint4 a0 = *(const uint4*)(A + aoff0 + k0);
        uint4 a1 = *(const uint4*)(A + aoff1 + k0);
        uint4 b0 = *(const uint4*)(Bt + boff + k0);
        __syncthreads();
        *(uint4*)&As[crow * 40 + cpart] = a0;
        *(uint4*)&As[(crow + 64) * 40 + cpart] = a1;
        *(uint4*)&Bs[crow * 40 + cpart] = b0;
        __syncthreads();

        bf16x8 af[4], bfr[2];
        const ushort* ab = &As[(wr * 64 + l) * 40 + quad * 8];
#pragma unroll
        for (int mt = 0; mt < 4; ++mt)
            af[mt] = *(const bf16x8*)(ab + mt * 16 * 40);
        const ushort* bb = &Bs[(wc * 32 + l) * 40 + quad * 8];
#pragma unroll
        for (int nt = 0; nt < 2; ++nt)
            bfr[nt] = *(const bf16x8*)(bb + nt * 16 * 40);
#pragma unroll
        for (int mt = 0; mt < 4; ++mt)
#pragma unroll
            for (int nt = 0; nt < 2; ++nt)
                acc[mt][nt] = __builtin_amdgcn_mfma_f32_16x16x32_bf16(
                    af[mt], bfr[nt], acc[mt][nt], 0, 0, 0);
    }

#pragma unroll
    for (int mt = 0; mt < 4; ++mt)
#pragma unroll
        for (int nt = 0; nt < 2; ++nt)
#pragma unroll
            for (int reg = 0; reg < 4; ++reg) {
                int r = m0 + wr * 64 + mt * 16 + quad * 4 + reg;
                int c = n0 + wc * 32 + nt * 16 + l;
                if (r < M) C[(size_t)r * N + c] = f2b(acc[mt][nt][reg]);
            }
}

// ---------------------------------------------------------------------------
// Per-row symmetric int8 quantization, W=256: wave per node, lane holds 4.
__global__ __launch_bounds__(256)
void quant_rows_256(const ushort* __restrict__ Sb, char* __restrict__ Q,
                    float* __restrict__ scale, int n) {
    const int wave = threadIdx.x >> 6;
    const int lane = threadIdx.x & 63;
    const int node = blockIdx.x * 4 + wave;
    if (node >= n) return;
    ushort4 x = *(const ushort4*)(Sb + (size_t)node * 256 + lane * 4);
    float f0 = b2f(x.x), f1 = b2f(x.y), f2 = b2f(x.z), f3 = b2f(x.w);
    float am = fmaxf(fmaxf(fabsf(f0), fabsf(f1)), fmaxf(fabsf(f2), fabsf(f3)));
#pragma unroll
    for (int s = 32; s >= 1; s >>= 1) am = fmaxf(am, __shfl_xor(am, s));
    float inv = am > 0.f ? 127.f / am : 0.f;
    int q0 = (int)rintf(f0 * inv), q1 = (int)rintf(f1 * inv);
    int q2 = (int)rintf(f2 * inv), q3 = (int)rintf(f3 * inv);
    uint qp = ((uint)q0 & 0xff) | (((uint)q1 & 0xff) << 8) |
              (((uint)q2 & 0xff) << 16) | (((uint)q3 & 0xff) << 24);
    *(uint*)(Q + (size_t)node * 256 + lane * 4) = qp;
    if (lane == 0) scale[node] = am * (1.f / 127.f);
}

// Per-row symmetric int8 quantization, W=64: wave per node, lane holds 1.
__global__ __launch_bounds__(256)
void quant_rows_64(const ushort* __restrict__ Sb, char* __restrict__ Q,
                   float* __restrict__ scale, int n) {
    const int wave = threadIdx.x >> 6;
    const int lane = threadIdx.x & 63;
    const int node = blockIdx.x * 4 + wave;
    if (node >= n) return;
    float f = b2f(Sb[(size_t)node * 64 + lane]);
    float am = fabsf(f);
#pragma unroll
    for (int s = 32; s >= 1; s >>= 1) am = fmaxf(am, __shfl_xor(am, s));
    float inv = am > 0.f ? 127.f / am : 0.f;
    Q[(size_t)node * 64 + lane] = (char)(int)rintf(f * inv);
    if (lane == 0) scale[node] = am * (1.f / 127.f);
}

// ---------------------------------------------------------------------------
// SpMM layer1: H = relu(sum_e w_e * Q1[c_e] + b1). Wave per node; lane = 4
// features (4B gather/edge); one 8B ew load per edge; 8-edge unroll.
__global__ __launch_bounds__(256)
void spmm1_q(const char* __restrict__ Q, const int2* __restrict__ ew,
             const int* __restrict__ rp, const float* __restrict__ bias,
             ushort* __restrict__ H, int n) {
    const int wave = threadIdx.x >> 6;
    const int lane = threadIdx.x & 63;
    const int node = blockIdx.x * 4 + wave;
    if (node >= n) return;
    const int e0 = rp[node], e1 = rp[node + 1];
    float a0 = 0.f, a1 = 0.f, a2 = 0.f, a3 = 0.f;
    int e = e0;
    for (; e + 7 < e1; e += 8) {
#pragma unroll
        for (int u = 0; u < 8; ++u) {
            int2 m = ew[e + u];
            float w = __int_as_float(m.y);
            char4 q = *(const char4*)(Q + (size_t)m.x * 256 + lane * 4);
            a0 += w * (float)q.x;
            a1 += w * (float)q.y;
            a2 += w * (float)q.z;
            a3 += w * (float)q.w;
        }
    }
    for (; e < e1; ++e) {
        int2 m = ew[e];
        float w = __int_as_float(m.y);
        char4 q = *(const char4*)(Q + (size_t)m.x * 256 + lane * 4);
        a0 += w * (float)q.x;
        a1 += w * (float)q.y;
        a2 += w * (float)q.z;
        a3 += w * (float)q.w;
    }
    float4 b = *(const float4*)(bias + lane * 4);
    ushort4 r;
    r.x = f2b(fmaxf(a0 + b.x, 0.f));
    r.y = f2b(fmaxf(a1 + b.y, 0.f));
    r.z = f2b(fmaxf(a2 + b.z, 0.f));
    r.w = f2b(fmaxf(a3 + b.w, 0.f));
    *(ushort4*)(H + (size_t)node * 256 + lane * 4) = r;
}

// ---------------------------------------------------------------------------
// SpMM layer2: out = sum_e w_e * Q2[c_e] + b2. Wave per node; lane = feature
// (1B gather/edge); one 8B ew load per edge; 8-edge unroll.
__global__ __launch_bounds__(256)
void spmm2_q(const char* __restrict__ Q, const int2* __restrict__ ew,
             const int* __restrict__ rp, const float* __restrict__ bias,
             float* __restrict__ O, int n) {
    const int wave = threadIdx.x >> 6;
    const int lane = threadIdx.x & 63;
    const int node = blockIdx.x * 4 + wave;
    if (node >= n) return;
    const int e0 = rp[node], e1 = rp[node + 1];
    float acc = 0.f;
    int e = e0;
    for (; e + 7 < e1; e += 8) {
#pragma unroll
        for (int u = 0; u < 8; ++u) {
            int2 m = ew[e + u];
            acc += __int_as_float(m.y) * (float)Q[(size_t)m.x * 64 + lane];
        }
    }
    for (; e < e1; ++e) {
        int2 m = ew[e];
        acc += __int_as_float(m.y) * (float)Q[(size_t)m.x * 64 + lane];
    }
    O[(size_t)node * 64 + lane] = acc + bias[lane];
}

// ---------------------------------------------------------------------------
static inline size_t alignup(size_t x) { return (x + 255) & ~(size_t)255; }

extern "C" void kernel_launch(void* const* d_in, const int* in_sizes, int n_in,
                              void* d_out, int out_size, void* d_ws, size_t ws_size,
                              hipStream_t stream) {
    const float* X  = (const float*)d_in[0];
    const float* ev = (const float*)d_in[1];
    const float* W1 = (const float*)d_in[2];
    const float* b1 = (const float*)d_in[3];
    const float* W2 = (const float*)d_in[4];
    const float* b2 = (const float*)d_in[5];
    const int*  row = (const int*)d_in[6];
    const int*  col = (const int*)d_in[7];
    float* out = (float*)d_out;

    const int n = in_sizes[0] / IN_SIZE;   // 100000
    const int E = in_sizes[1];             // 3200000

    char* p = (char*)d_ws;
    ushort* bufA = (ushort*)p; p += alignup((size_t)n * HID * 2);   // C1, then H
    char*   Q1   = (char*)p;   p += alignup((size_t)n * HID);
    float*  s1   = (float*)p;  p += alignup((size_t)n * 4);
    ushort* hw2  = (ushort*)p; p += alignup((size_t)n * OUTF * 2);
    char*   Q2   = (char*)p;   p += alignup((size_t)n * OUTF);
    float*  s2   = (float*)p;  p += alignup((size_t)n * 4);
    ushort* W1T  = (ushort*)p; p += alignup((size_t)IN_SIZE * HID * 2);
    ushort* W2T  = (ushort*)p; p += alignup((size_t)HID * OUTF * 2);
    int*    rp   = (int*)p;    p += alignup((size_t)(n + 1) * 4);
    int2*   ewb  = (int2*)p;   p += alignup((size_t)E * 8);          // ew1, then ew2

    build_rowptr<<<(n + 1 + 255) / 256, 256, 0, stream>>>(row, rp, n, E);
    transpose_cast<<<dim3(HID, 1), 256, 0, stream>>>(W1, W1T, IN_SIZE, HID);
    transpose_cast<<<dim3(OUTF, 1), 256, 0, stream>>>(W2, W2T, HID, OUTF);

    // C1 = bf16(X) @ W1  [n,256] bf16 ; X read exactly once
    gemm1_cast<<<(n + 63) / 64, 256, 0, stream>>>(X, W1T, bufA, n);

    // Q1,s1 = rowquant(C1)
    quant_rows_256<<<(n + 3) / 4, 256, 0, stream>>>(bufA, Q1, s1, n);

    // ew = {col, vals*s1[col]}
    prep_edges<<<(E + 255) / 256, 256, 0, stream>>>(ev, col, s1, ewb, E);

    // H = relu(A @ deq(Q1) + b1)  [n,256] bf16 (overlays C1)
    spmm1_q<<<(n + 3) / 4, 256, 0, stream>>>(Q1, ewb, rp, b1, bufA, n);

    // hw2 = H @ W2  [n,64] bf16
    dim3 g2((n + 127) / 128, OUTF / 64);
    gemm_bf16<<<g2, 256, 0, stream>>>(bufA, W2T, hw2, n, OUTF, HID);

    // Q2,s2 = rowquant(hw2)
    quant_rows_64<<<(n + 3) / 4, 256, 0, stream>>>(hw2, Q2, s2, n);

    // ew = {col, vals*s2[col]}
    prep_edges<<<(E + 255) / 256, 256, 0, stream>>>(ev, col, s2, ewb, E);

    // out = A @ deq(Q2) + b2  [n,64] fp32
    spmm2_q<<<(n + 3) / 4, 256, 0, stream>>>(Q2, ewb, rp, b2, out, n);
}

// Round 6
// 509.476 us; speedup vs baseline: 1.1204x; 1.1204x over previous
//
#include <hip/hip_runtime.h>

// GCN: out = A*(relu(A*(X*W1)+b1)*W2)+b2, A sparse COO, sorted row[].
// N=100000, E=3200000, IN=256, HID=256, OUT=64.
// Pipeline (7 launches):
//   setup: rowptr + W1T + W2T (fused, block ranges)
//   gemm1: C1 = bf16(X)@W1 (BM=128,BN=256; X read once) + row-absmax -> s1
//   fuse1: Q1 = int8(C1/s1) elementwise  ||  ew = {col, vals*s1[col]}
//   spmm1: H = relu(A@deq(Q1)+b1) -> bf16 (overlays C1)
//   gemm2: hw2 = H@W2 (BM=128,BN=64) + row-absmax -> s2
//   fuse2: Q2 = int8(hw2/s2)  ||  ew = {col, vals*s2[col]}
//   spmm2: out = A@deq(Q2)+b2 -> fp32

constexpr int IN_SIZE = 256;
constexpr int HID = 256;
constexpr int OUTF = 64;

typedef __bf16 bf16x8 __attribute__((ext_vector_type(8)));
typedef float f32x4 __attribute__((ext_vector_type(4)));

__device__ __forceinline__ ushort f2b(float f) {
    uint u = __float_as_uint(f);
    uint r = (u + 0x7fffu + ((u >> 16) & 1u)) >> 16;   // RNE
    return (ushort)r;
}
__device__ __forceinline__ float b2f(ushort h) {
    return __uint_as_float(((uint)h) << 16);
}

// ---------------------------------------------------------------------------
// setup: blocks [0,rpB): row_ptr; [rpB,rpB+256): W1T; [rpB+256,rpB+320): W2T
__global__ void setup_kernel(const int* __restrict__ row, int* __restrict__ rp,
                             const float* __restrict__ W1, ushort* __restrict__ W1T,
                             const float* __restrict__ W2, ushort* __restrict__ W2T,
                             int n, int E, int rpB) {
    int b = blockIdx.x;
    if (b < rpB) {
        int i = b * 256 + threadIdx.x;
        if (i > n) return;
        int lo = 0, hi = E;
        while (lo < hi) {
            int mid = (lo + hi) >> 1;
            if (row[mid] < i) lo = mid + 1; else hi = mid;
        }
        rp[i] = lo;
    } else if (b < rpB + 256) {
        int nn = b - rpB;          // output row of W1T (0..255)
        int k = threadIdx.x;       // 0..255
        W1T[(size_t)nn * 256 + k] = f2b(W1[(size_t)k * 256 + nn]);
    } else {
        int nn = b - rpB - 256;    // output row of W2T (0..63)
        int k = threadIdx.x;       // 0..255
        W2T[(size_t)nn * 256 + k] = f2b(W2[(size_t)k * 64 + nn]);
    }
}

// ---------------------------------------------------------------------------
// GEMM1: C[M,256] = bf16(A_f32[M,256]) * Bt[256,256]^T. BM=128, BN=256, BK=32.
// 4 waves 2x2; wave tile 64x128. Epilogue: per-row absmax -> s1.
__global__ __launch_bounds__(256, 2)
void gemm1_cast_n256(const float* __restrict__ A, const ushort* __restrict__ Bt,
                     ushort* __restrict__ C, float* __restrict__ s1, int M) {
    constexpr int K = 256;
    __shared__ ushort As[128 * 40];
    __shared__ ushort Bs[256 * 40];
    __shared__ float red[2][128];
    const int tid = threadIdx.x;
    const int wave = tid >> 6, lane = tid & 63;
    const int quad = lane >> 4, l = lane & 15;
    const int wr = wave >> 1, wc = wave & 1;
    const int m0 = blockIdx.x * 128;

    const int ar = tid >> 1;
    const int ah = (tid & 1) * 16;
    const size_t aoff = (size_t)min(m0 + ar, M - 1) * K + ah;
    const int bn = tid >> 2;
    const int bkp = (tid & 3) * 8;

    f32x4 acc[4][8] = {};

    for (int k0 = 0; k0 < K; k0 += 32) {
        float4 a0 = *(const float4*)(A + aoff + k0);
        float4 a1 = *(const float4*)(A + aoff + k0 + 4);
        float4 a2 = *(const float4*)(A + aoff + k0 + 8);
        float4 a3 = *(const float4*)(A + aoff + k0 + 12);
        uint4 bv[4];
#pragma unroll
        for (int j = 0; j < 4; ++j)
            bv[j] = *(const uint4*)(Bt + (size_t)(bn + 64 * j) * K + k0 + bkp);
        uint4 pa0, pa1;
        pa0.x = (uint)f2b(a0.x) | ((uint)f2b(a0.y) << 16);
        pa0.y = (uint)f2b(a0.z) | ((uint)f2b(a0.w) << 16);
        pa0.z = (uint)f2b(a1.x) | ((uint)f2b(a1.y) << 16);
        pa0.w = (uint)f2b(a1.z) | ((uint)f2b(a1.w) << 16);
        pa1.x = (uint)f2b(a2.x) | ((uint)f2b(a2.y) << 16);
        pa1.y = (uint)f2b(a2.z) | ((uint)f2b(a2.w) << 16);
        pa1.z = (uint)f2b(a3.x) | ((uint)f2b(a3.y) << 16);
        pa1.w = (uint)f2b(a3.z) | ((uint)f2b(a3.w) << 16);
        __syncthreads();
        *(uint4*)&As[ar * 40 + ah] = pa0;
        *(uint4*)&As[ar * 40 + ah + 8] = pa1;
#pragma unroll
        for (int j = 0; j < 4; ++j)
            *(uint4*)&Bs[(bn + 64 * j) * 40 + bkp] = bv[j];
        __syncthreads();

        bf16x8 af[4], bfr[8];
        const ushort* ab = &As[(wr * 64 + l) * 40 + quad * 8];
#pragma unroll
        for (int mt = 0; mt < 4; ++mt)
            af[mt] = *(const bf16x8*)(ab + mt * 16 * 40);
        const ushort* bb = &Bs[(wc * 128 + l) * 40 + quad * 8];
#pragma unroll
        for (int nt = 0; nt < 8; ++nt)
            bfr[nt] = *(const bf16x8*)(bb + nt * 16 * 40);
#pragma unroll
        for (int mt = 0; mt < 4; ++mt)
#pragma unroll
            for (int nt = 0; nt < 8; ++nt)
                acc[mt][nt] = __builtin_amdgcn_mfma_f32_16x16x32_bf16(
                    af[mt], bfr[nt], acc[mt][nt], 0, 0, 0);
    }

    // C-writes + per-lane row absmax over this wave's 128 cols
    float rmax[4][4];
#pragma unroll
    for (int mt = 0; mt < 4; ++mt)
#pragma unroll
        for (int reg = 0; reg < 4; ++reg) {
            float m = 0.f;
#pragma unroll
            for (int nt = 0; nt < 8; ++nt)
                m = fmaxf(m, fabsf(acc[mt][nt][reg]));
            rmax[mt][reg] = m;
        }
#pragma unroll
    for (int mt = 0; mt < 4; ++mt)
#pragma unroll
        for (int nt = 0; nt < 8; ++nt)
#pragma unroll
            for (int reg = 0; reg < 4; ++reg) {
                int r = m0 + wr * 64 + mt * 16 + quad * 4 + reg;
                int c = wc * 128 + nt * 16 + l;
                if (r < M) C[(size_t)r * 256 + c] = f2b(acc[mt][nt][reg]);
            }
    // reduce rmax across the 16 l-lanes (xor 1,2,4,8 stays inside quad)
#pragma unroll
    for (int s = 1; s <= 8; s <<= 1)
#pragma unroll
        for (int mt = 0; mt < 4; ++mt)
#pragma unroll
            for (int reg = 0; reg < 4; ++reg)
                rmax[mt][reg] = fmaxf(rmax[mt][reg], __shfl_xor(rmax[mt][reg], s));
    if (l < 4) {
#pragma unroll
        for (int mt = 0; mt < 4; ++mt)
            red[wc][wr * 64 + mt * 16 + quad * 4 + l] = rmax[mt][l];
    }
    __syncthreads();
    if (tid < 128) {
        int r = m0 + tid;
        if (r < M) s1[r] = fmaxf(red[0][tid], red[1][tid]) * (1.f / 127.f);
    }
}

// ---------------------------------------------------------------------------
// GEMM2: C[M,64] = A[M,256] * Bt[64,256]^T bf16. BM=128, BN=64 (full width).
// Epilogue: per-row absmax -> s2.
__global__ __launch_bounds__(256, 4)
void gemm2_bf16(const ushort* __restrict__ A, const ushort* __restrict__ Bt,
                ushort* __restrict__ C, float* __restrict__ s2, int M) {
    constexpr int K = 256;
    __shared__ ushort As[128 * 40];
    __shared__ ushort Bs[64 * 40];
    __shared__ float red[2][128];
    const int tid = threadIdx.x;
    const int wave = tid >> 6, lane = tid & 63;
    const int quad = lane >> 4, l = lane & 15;
    const int wr = wave >> 1, wc = wave & 1;
    const int m0 = blockIdx.x * 128;

    const int crow = tid >> 2;
    const int cpart = (tid & 3) * 8;
    const size_t aoff0 = (size_t)min(m0 + crow, M - 1) * K + cpart;
    const size_t aoff1 = (size_t)min(m0 + crow + 64, M - 1) * K + cpart;
    const size_t boff  = (size_t)crow * K + cpart;

    f32x4 acc[4][2] = {};

    for (int k0 = 0; k0 < K; k0 += 32) {
        uint4 a0 = *(const uint4*)(A + aoff0 + k0);
        uint4 a1 = *(const uint4*)(A + aoff1 + k0);
        uint4 b0 = *(const uint4*)(Bt + boff + k0);
        __syncthreads();
        *(uint4*)&As[crow * 40 + cpart] = a0;
        *(uint4*)&As[(crow + 64) * 40 + cpart] = a1;
        *(uint4*)&Bs[crow * 40 + cpart] = b0;
        __syncthreads();

        bf16x8 af[4], bfr[2];
        const ushort* ab = &As[(wr * 64 + l) * 40 + quad * 8];
#pragma unroll
        for (int mt = 0; mt < 4; ++mt)
            af[mt] = *(const bf16x8*)(ab + mt * 16 * 40);
        const ushort* bb = &Bs[(wc * 32 + l) * 40 + quad * 8];
#pragma unroll
        for (int nt = 0; nt < 2; ++nt)
            bfr[nt] = *(const bf16x8*)(bb + nt * 16 * 40);
#pragma unroll
        for (int mt = 0; mt < 4; ++mt)
#pragma unroll
            for (int nt = 0; nt < 2; ++nt)
                acc[mt][nt] = __builtin_amdgcn_mfma_f32_16x16x32_bf16(
                    af[mt], bfr[nt], acc[mt][nt], 0, 0, 0);
    }

    float rmax[4][4];
#pragma unroll
    for (int mt = 0; mt < 4; ++mt)
#pragma unroll
        for (int reg = 0; reg < 4; ++reg)
            rmax[mt][reg] = fmaxf(fabsf(acc[mt][0][reg]), fabsf(acc[mt][1][reg]));
#pragma unroll
    for (int mt = 0; mt < 4; ++mt)
#pragma unroll
        for (int nt = 0; nt < 2; ++nt)
#pragma unroll
            for (int reg = 0; reg < 4; ++reg) {
                int r = m0 + wr * 64 + mt * 16 + quad * 4 + reg;
                int c = wc * 32 + nt * 16 + l;
                if (r < M) C[(size_t)r * 64 + c] = f2b(acc[mt][nt][reg]);
            }
#pragma unroll
    for (int s = 1; s <= 8; s <<= 1)
#pragma unroll
        for (int mt = 0; mt < 4; ++mt)
#pragma unroll
            for (int reg = 0; reg < 4; ++reg)
                rmax[mt][reg] = fmaxf(rmax[mt][reg], __shfl_xor(rmax[mt][reg], s));
    if (l < 4) {
#pragma unroll
        for (int mt = 0; mt < 4; ++mt)
            red[wc][wr * 64 + mt * 16 + quad * 4 + l] = rmax[mt][l];
    }
    __syncthreads();
    if (tid < 128) {
        int r = m0 + tid;
        if (r < M) s2[r] = fmaxf(red[0][tid], red[1][tid]) * (1.f / 127.f);
    }
}

// ---------------------------------------------------------------------------
// fuse: elementwise int8 quant (scales precomputed) || edge prep.
// logw = 8 (width 256) or 6 (width 64). Quant: thread = 8 elems.
__global__ __launch_bounds__(256)
void fuse_quant_prep(const ushort* __restrict__ Sb, const float* __restrict__ s,
                     char* __restrict__ Q, int total_elems,
                     const float* __restrict__ vals, const int* __restrict__ col,
                     int2* __restrict__ ew, int E, int quantBlocks, int logw) {
    int b = blockIdx.x;
    if (b < quantBlocks) {
        int i = (b * 256 + threadIdx.x) * 8;
        if (i >= total_elems) return;
        int r = i >> logw;
        float sc = s[r];
        float inv = sc > 0.f ? 1.f / sc : 0.f;
        uint4 x = *(const uint4*)(Sb + i);
        float f[8];
        f[0] = b2f((ushort)x.x); f[1] = b2f((ushort)(x.x >> 16));
        f[2] = b2f((ushort)x.y); f[3] = b2f((ushort)(x.y >> 16));
        f[4] = b2f((ushort)x.z); f[5] = b2f((ushort)(x.z >> 16));
        f[6] = b2f((ushort)x.w); f[7] = b2f((ushort)(x.w >> 16));
        uint2 o;
        o.x = ((uint)((int)rintf(f[0] * inv) & 0xff)) |
              ((uint)((int)rintf(f[1] * inv) & 0xff) << 8) |
              ((uint)((int)rintf(f[2] * inv) & 0xff) << 16) |
              ((uint)((int)rintf(f[3] * inv) & 0xff) << 24);
        o.y = ((uint)((int)rintf(f[4] * inv) & 0xff)) |
              ((uint)((int)rintf(f[5] * inv) & 0xff) << 8) |
              ((uint)((int)rintf(f[6] * inv) & 0xff) << 16) |
              ((uint)((int)rintf(f[7] * inv) & 0xff) << 24);
        *(uint2*)(Q + i) = o;
    } else {
        int e = (b - quantBlocks) * 256 + threadIdx.x;
        if (e >= E) return;
        int c = col[e];
        ew[e] = make_int2(c, __float_as_int(vals[e] * s[c]));
    }
}

// ---------------------------------------------------------------------------
// SpMM layer1: H = relu(sum_e w_e * Q1[c_e] + b1). Wave per node; lane = 4
// features (4B gather/edge); one 8B ew load per edge; 8-edge unroll.
__global__ __launch_bounds__(256)
void spmm1_q(const char* __restrict__ Q, const int2* __restrict__ ew,
             const int* __restrict__ rp, const float* __restrict__ bias,
             ushort* __restrict__ H, int n) {
    const int wave = threadIdx.x >> 6;
    const int lane = threadIdx.x & 63;
    const int node = blockIdx.x * 4 + wave;
    if (node >= n) return;
    const int e0 = rp[node], e1 = rp[node + 1];
    float a0 = 0.f, a1 = 0.f, a2 = 0.f, a3 = 0.f;
    int e = e0;
    for (; e + 7 < e1; e += 8) {
#pragma unroll
        for (int u = 0; u < 8; ++u) {
            int2 m = ew[e + u];
            float w = __int_as_float(m.y);
            char4 q = *(const char4*)(Q + (size_t)m.x * 256 + lane * 4);
            a0 += w * (float)q.x;
            a1 += w * (float)q.y;
            a2 += w * (float)q.z;
            a3 += w * (float)q.w;
        }
    }
    for (; e < e1; ++e) {
        int2 m = ew[e];
        float w = __int_as_float(m.y);
        char4 q = *(const char4*)(Q + (size_t)m.x * 256 + lane * 4);
        a0 += w * (float)q.x;
        a1 += w * (float)q.y;
        a2 += w * (float)q.z;
        a3 += w * (float)q.w;
    }
    float4 b = *(const float4*)(bias + lane * 4);
    ushort4 r;
    r.x = f2b(fmaxf(a0 + b.x, 0.f));
    r.y = f2b(fmaxf(a1 + b.y, 0.f));
    r.z = f2b(fmaxf(a2 + b.z, 0.f));
    r.w = f2b(fmaxf(a3 + b.w, 0.f));
    *(ushort4*)(H + (size_t)node * 256 + lane * 4) = r;
}

// ---------------------------------------------------------------------------
// SpMM layer2: out = sum_e w_e * Q2[c_e] + b2. Wave per node; lane = feature
// (1B gather/edge, one 64B line per edge); 16-edge unroll.
__global__ __launch_bounds__(256)
void spmm2_q(const char* __restrict__ Q, const int2* __restrict__ ew,
             const int* __restrict__ rp, const float* __restrict__ bias,
             float* __restrict__ O, int n) {
    const int wave = threadIdx.x >> 6;
    const int lane = threadIdx.x & 63;
    const int node = blockIdx.x * 4 + wave;
    if (node >= n) return;
    const int e0 = rp[node], e1 = rp[node + 1];
    float acc = 0.f;
    int e = e0;
    for (; e + 15 < e1; e += 16) {
#pragma unroll
        for (int u = 0; u < 16; ++u) {
            int2 m = ew[e + u];
            acc += __int_as_float(m.y) * (float)Q[(size_t)m.x * 64 + lane];
        }
    }
    for (; e + 3 < e1; e += 4) {
#pragma unroll
        for (int u = 0; u < 4; ++u) {
            int2 m = ew[e + u];
            acc += __int_as_float(m.y) * (float)Q[(size_t)m.x * 64 + lane];
        }
    }
    for (; e < e1; ++e) {
        int2 m = ew[e];
        acc += __int_as_float(m.y) * (float)Q[(size_t)m.x * 64 + lane];
    }
    O[(size_t)node * 64 + lane] = acc + bias[lane];
}

// ---------------------------------------------------------------------------
static inline size_t alignup(size_t x) { return (x + 255) & ~(size_t)255; }

extern "C" void kernel_launch(void* const* d_in, const int* in_sizes, int n_in,
                              void* d_out, int out_size, void* d_ws, size_t ws_size,
                              hipStream_t stream) {
    const float* X  = (const float*)d_in[0];
    const float* ev = (const float*)d_in[1];
    const float* W1 = (const float*)d_in[2];
    const float* b1 = (const float*)d_in[3];
    const float* W2 = (const float*)d_in[4];
    const float* b2 = (const float*)d_in[5];
    const int*  row = (const int*)d_in[6];
    const int*  col = (const int*)d_in[7];
    float* out = (float*)d_out;

    const int n = in_sizes[0] / IN_SIZE;   // 100000
    const int E = in_sizes[1];             // 3200000

    char* p = (char*)d_ws;
    ushort* bufA = (ushort*)p; p += alignup((size_t)n * HID * 2);   // C1, then H
    char*   Q1   = (char*)p;   p += alignup((size_t)n * HID);
    float*  s1   = (float*)p;  p += alignup((size_t)n * 4);
    ushort* hw2  = (ushort*)p; p += alignup((size_t)n * OUTF * 2);
    char*   Q2   = (char*)p;   p += alignup((size_t)n * OUTF);
    float*  s2   = (float*)p;  p += alignup((size_t)n * 4);
    ushort* W1T  = (ushort*)p; p += alignup((size_t)IN_SIZE * HID * 2);
    ushort* W2T  = (ushort*)p; p += alignup((size_t)HID * OUTF * 2);
    int*    rp   = (int*)p;    p += alignup((size_t)(n + 1) * 4);
    int2*   ewb  = (int2*)p;   p += alignup((size_t)E * 8);

    // setup: rowptr + both weight transposes
    const int rpB = (n + 1 + 255) / 256;
    setup_kernel<<<rpB + 256 + 64, 256, 0, stream>>>(row, rp, W1, W1T, W2, W2T,
                                                     n, E, rpB);

    // C1 = bf16(X) @ W1, s1 = rowabsmax/127
    gemm1_cast_n256<<<(n + 127) / 128, 256, 0, stream>>>(X, W1T, bufA, s1, n);

    // Q1 = quant(C1,s1) || ew = {col, vals*s1[col]}
    {
        int qB = ((n * HID / 8) + 255) / 256;
        int pB = (E + 255) / 256;
        fuse_quant_prep<<<qB + pB, 256, 0, stream>>>(bufA, s1, Q1, n * HID,
                                                     ev, col, ewb, E, qB, 8);
    }

    // H = relu(A @ deq(Q1) + b1)  (overlays C1)
    spmm1_q<<<(n + 3) / 4, 256, 0, stream>>>(Q1, ewb, rp, b1, bufA, n);

    // hw2 = H @ W2, s2 = rowabsmax/127
    gemm2_bf16<<<(n + 127) / 128, 256, 0, stream>>>(bufA, W2T, hw2, s2, n);

    // Q2 = quant(hw2,s2) || ew = {col, vals*s2[col]}
    {
        int qB = ((n * OUTF / 8) + 255) / 256;
        int pB = (E + 255) / 256;
        fuse_quant_prep<<<qB + pB, 256, 0, stream>>>(hw2, s2, Q2, n * OUTF,
                                                     ev, col, ewb, E, qB, 6);
    }

    // out = A @ deq(Q2) + b2
    spmm2_q<<<(n + 3) / 4, 256, 0, stream>>>(Q2, ewb, rp, b2, out, n);
}

// Round 7
// 470.945 us; speedup vs baseline: 1.2121x; 1.0818x over previous
//
#include <hip/hip_runtime.h>

// GCN: out = A*(relu(A*(X*W1)+b1)*W2)+b2, A sparse COO, sorted row[].
// N=100000, E=3200000, IN=256, HID=256, OUT=64.
// Pipeline (7 launches, int8 gather sources, no bf16 intermediate roundtrip):
//   setup: rowptr + W1T + W2T
//   gemm1: Q1,s1 = int8rowquant(bf16(X)@W1)   (512thr, BM=128 BN=256)
//   prep1: ew = {col<<8, vals*s1[col]}
//   spmm1: H = relu(A@deq(Q1)+b1) -> bf16
//   gemm2: Q2,s2 = int8rowquant(H@W2)         (256thr, BM=128 BN=64)
//   prep2: ew = {col<<6, vals*s2[col]}
//   spmm2: out = A@deq(Q2)+b2 -> fp32

constexpr int IN_SIZE = 256;
constexpr int HID = 256;
constexpr int OUTF = 64;

typedef __bf16 bf16x8 __attribute__((ext_vector_type(8)));
typedef float f32x4 __attribute__((ext_vector_type(4)));

__device__ __forceinline__ ushort f2b(float f) {
    uint u = __float_as_uint(f);
    uint r = (u + 0x7fffu + ((u >> 16) & 1u)) >> 16;   // RNE
    return (ushort)r;
}
__device__ __forceinline__ float b2f(ushort h) {
    return __uint_as_float(((uint)h) << 16);
}

// ---------------------------------------------------------------------------
// setup: blocks [0,rpB): row_ptr; [rpB,rpB+256): W1T; [rpB+256,rpB+320): W2T
__global__ void setup_kernel(const int* __restrict__ row, int* __restrict__ rp,
                             const float* __restrict__ W1, ushort* __restrict__ W1T,
                             const float* __restrict__ W2, ushort* __restrict__ W2T,
                             int n, int E, int rpB) {
    int b = blockIdx.x;
    if (b < rpB) {
        int i = b * 256 + threadIdx.x;
        if (i > n) return;
        int lo = 0, hi = E;
        while (lo < hi) {
            int mid = (lo + hi) >> 1;
            if (row[mid] < i) lo = mid + 1; else hi = mid;
        }
        rp[i] = lo;
    } else if (b < rpB + 256) {
        int nn = b - rpB;
        int k = threadIdx.x;
        W1T[(size_t)nn * 256 + k] = f2b(W1[(size_t)k * 256 + nn]);
    } else {
        int nn = b - rpB - 256;
        int k = threadIdx.x;
        W2T[(size_t)nn * 256 + k] = f2b(W2[(size_t)k * 64 + nn]);
    }
}

// prep: ew[e] = {col[e]<<shift (byte offset into Q), vals[e]*s[col[e]]}
__global__ void prep_edges(const float* __restrict__ vals, const int* __restrict__ col,
                           const float* __restrict__ s, int2* __restrict__ ew,
                           int E, int shift) {
    int e = blockIdx.x * 256 + threadIdx.x;
    if (e >= E) return;
    int c = col[e];
    ew[e] = make_int2(c << shift, __float_as_int(vals[e] * s[c]));
}

// ---------------------------------------------------------------------------
// GEMM1+quant: Q[M,256] int8, s1[M] from bf16(X_f32[M,256]) @ Bt[256,256]^T.
// BM=128, BN=256 (full width, X read once), BK=32. 512 threads = 8 waves in
// 2x4; wave tile 64x64 -> acc[4][4] (64 VGPRs).
__global__ __launch_bounds__(512)
void gemm1_q(const float* __restrict__ A, const ushort* __restrict__ Bt,
             char* __restrict__ Q, float* __restrict__ s1, int M) {
    constexpr int K = 256;
    __shared__ ushort As[128 * 40];
    __shared__ ushort Bs[256 * 40];
    __shared__ float red[4][128];
    __shared__ float fin[128];
    const int tid = threadIdx.x;
    const int wave = tid >> 6, lane = tid & 63;
    const int quad = lane >> 4, l = lane & 15;
    const int wr = wave >> 2, wc = wave & 3;     // 2 x 4 wave grid
    const int m0 = blockIdx.x * 128;

    // A staging: row ar=tid>>2 (0..127), 8 floats at ak=(tid&3)*8
    const int ar = tid >> 2;
    const int ak = (tid & 3) * 8;
    const size_t aoff = (size_t)min(m0 + ar, M - 1) * K + ak;
    // B staging: rows bn, bn+128; 8 bf16 at bkp
    const int bn = tid >> 2;
    const int bkp = (tid & 3) * 8;

    f32x4 acc[4][4] = {};

    for (int k0 = 0; k0 < K; k0 += 32) {
        float4 a0 = *(const float4*)(A + aoff + k0);
        float4 a1 = *(const float4*)(A + aoff + k0 + 4);
        uint4 bv0 = *(const uint4*)(Bt + (size_t)bn * K + k0 + bkp);
        uint4 bv1 = *(const uint4*)(Bt + (size_t)(bn + 128) * K + k0 + bkp);
        uint4 pa;
        pa.x = (uint)f2b(a0.x) | ((uint)f2b(a0.y) << 16);
        pa.y = (uint)f2b(a0.z) | ((uint)f2b(a0.w) << 16);
        pa.z = (uint)f2b(a1.x) | ((uint)f2b(a1.y) << 16);
        pa.w = (uint)f2b(a1.z) | ((uint)f2b(a1.w) << 16);
        __syncthreads();
        *(uint4*)&As[ar * 40 + ak] = pa;
        *(uint4*)&Bs[bn * 40 + bkp] = bv0;
        *(uint4*)&Bs[(bn + 128) * 40 + bkp] = bv1;
        __syncthreads();

        bf16x8 af[4], bfr[4];
#pragma unroll
        for (int mt = 0; mt < 4; ++mt)
            af[mt] = *(const bf16x8*)&As[(wr * 64 + mt * 16 + l) * 40 + quad * 8];
#pragma unroll
        for (int nt = 0; nt < 4; ++nt)
            bfr[nt] = *(const bf16x8*)&Bs[(wc * 64 + nt * 16 + l) * 40 + quad * 8];
#pragma unroll
        for (int mt = 0; mt < 4; ++mt)
#pragma unroll
            for (int nt = 0; nt < 4; ++nt)
                acc[mt][nt] = __builtin_amdgcn_mfma_f32_16x16x32_bf16(
                    af[mt], bfr[nt], acc[mt][nt], 0, 0, 0);
    }

    // per-lane row absmax over this wave's 64 cols
    float rmax[4][4];
#pragma unroll
    for (int mt = 0; mt < 4; ++mt)
#pragma unroll
        for (int reg = 0; reg < 4; ++reg) {
            float m = 0.f;
#pragma unroll
            for (int nt = 0; nt < 4; ++nt)
                m = fmaxf(m, fabsf(acc[mt][nt][reg]));
            rmax[mt][reg] = m;
        }
#pragma unroll
    for (int s = 1; s <= 8; s <<= 1)
#pragma unroll
        for (int mt = 0; mt < 4; ++mt)
#pragma unroll
            for (int reg = 0; reg < 4; ++reg)
                rmax[mt][reg] = fmaxf(rmax[mt][reg], __shfl_xor(rmax[mt][reg], s));
    if (l < 4) {
#pragma unroll
        for (int mt = 0; mt < 4; ++mt)
            red[wc][wr * 64 + mt * 16 + quad * 4 + l] = rmax[mt][l];
    }
    __syncthreads();
    if (tid < 128) {
        float m = fmaxf(fmaxf(red[0][tid], red[1][tid]),
                        fmaxf(red[2][tid], red[3][tid]));
        fin[tid] = m;
        int r = m0 + tid;
        if (r < M) s1[r] = m * (1.f / 127.f);
    }
    __syncthreads();

    // quantize acc -> int8 bytes
#pragma unroll
    for (int mt = 0; mt < 4; ++mt)
#pragma unroll
        for (int reg = 0; reg < 4; ++reg) {
            int rl = wr * 64 + mt * 16 + quad * 4 + reg;
            int r = m0 + rl;
            if (r >= M) continue;
            float m = fin[rl];
            float inv = m > 0.f ? 127.f / m : 0.f;
#pragma unroll
            for (int nt = 0; nt < 4; ++nt) {
                int c = wc * 64 + nt * 16 + l;
                Q[(size_t)r * 256 + c] = (char)(int)rintf(acc[mt][nt][reg] * inv);
            }
        }
}

// ---------------------------------------------------------------------------
// GEMM2+quant: Q[M,64] int8, s2[M] from A[M,256] bf16 @ Bt[64,256]^T.
// BM=128, BN=64 (full width), BK=32; 256 threads = 4 waves 2x2.
__global__ __launch_bounds__(256, 4)
void gemm2_q(const ushort* __restrict__ A, const ushort* __restrict__ Bt,
             char* __restrict__ Q, float* __restrict__ s2, int M) {
    constexpr int K = 256;
    __shared__ ushort As[128 * 40];
    __shared__ ushort Bs[64 * 40];
    __shared__ float red[2][128];
    __shared__ float fin[128];
    const int tid = threadIdx.x;
    const int wave = tid >> 6, lane = tid & 63;
    const int quad = lane >> 4, l = lane & 15;
    const int wr = wave >> 1, wc = wave & 1;
    const int m0 = blockIdx.x * 128;

    const int crow = tid >> 2;
    const int cpart = (tid & 3) * 8;
    const size_t aoff0 = (size_t)min(m0 + crow, M - 1) * K + cpart;
    const size_t aoff1 = (size_t)min(m0 + crow + 64, M - 1) * K + cpart;
    const size_t boff  = (size_t)crow * K + cpart;

    f32x4 acc[4][2] = {};

    for (int k0 = 0; k0 < K; k0 += 32) {
        uint4 a0 = *(const uint4*)(A + aoff0 + k0);
        uint4 a1 = *(const uint4*)(A + aoff1 + k0);
        uint4 b0 = *(const uint4*)(Bt + boff + k0);
        __syncthreads();
        *(uint4*)&As[crow * 40 + cpart] = a0;
        *(uint4*)&As[(crow + 64) * 40 + cpart] = a1;
        *(uint4*)&Bs[crow * 40 + cpart] = b0;
        __syncthreads();

        bf16x8 af[4], bfr[2];
        const ushort* ab = &As[(wr * 64 + l) * 40 + quad * 8];
#pragma unroll
        for (int mt = 0; mt < 4; ++mt)
            af[mt] = *(const bf16x8*)(ab + mt * 16 * 40);
        const ushort* bb = &Bs[(wc * 32 + l) * 40 + quad * 8];
#pragma unroll
        for (int nt = 0; nt < 2; ++nt)
            bfr[nt] = *(const bf16x8*)(bb + nt * 16 * 40);
#pragma unroll
        for (int mt = 0; mt < 4; ++mt)
#pragma unroll
            for (int nt = 0; nt < 2; ++nt)
                acc[mt][nt] = __builtin_amdgcn_mfma_f32_16x16x32_bf16(
                    af[mt], bfr[nt], acc[mt][nt], 0, 0, 0);
    }

    float rmax[4][4];
#pragma unroll
    for (int mt = 0; mt < 4; ++mt)
#pragma unroll
        for (int reg = 0; reg < 4; ++reg)
            rmax[mt][reg] = fmaxf(fabsf(acc[mt][0][reg]), fabsf(acc[mt][1][reg]));
#pragma unroll
    for (int s = 1; s <= 8; s <<= 1)
#pragma unroll
        for (int mt = 0; mt < 4; ++mt)
#pragma unroll
            for (int reg = 0; reg < 4; ++reg)
                rmax[mt][reg] = fmaxf(rmax[mt][reg], __shfl_xor(rmax[mt][reg], s));
    if (l < 4) {
#pragma unroll
        for (int mt = 0; mt < 4; ++mt)
            red[wc][wr * 64 + mt * 16 + quad * 4 + l] = rmax[mt][l];
    }
    __syncthreads();
    if (tid < 128) {
        float m = fmaxf(red[0][tid], red[1][tid]);
        fin[tid] = m;
        int r = m0 + tid;
        if (r < M) s2[r] = m * (1.f / 127.f);
    }
    __syncthreads();

#pragma unroll
    for (int mt = 0; mt < 4; ++mt)
#pragma unroll
        for (int reg = 0; reg < 4; ++reg) {
            int rl = wr * 64 + mt * 16 + quad * 4 + reg;
            int r = m0 + rl;
            if (r >= M) continue;
            float m = fin[rl];
            float inv = m > 0.f ? 127.f / m : 0.f;
#pragma unroll
            for (int nt = 0; nt < 2; ++nt) {
                int c = wc * 32 + nt * 16 + l;
                Q[(size_t)r * 64 + c] = (char)(int)rintf(acc[mt][nt][reg] * inv);
            }
        }
}

// ---------------------------------------------------------------------------
// SpMM layer1: H = relu(sum_e w_e * Q1[c_e] + b1). Wave per node; lane = 4
// features (4B gather/edge); one 8B ew load per edge; 8-edge unroll.
// ew.x is a pre-shifted byte offset (col*256).
__global__ __launch_bounds__(256)
void spmm1_q(const char* __restrict__ Q, const int2* __restrict__ ew,
             const int* __restrict__ rp, const float* __restrict__ bias,
             ushort* __restrict__ H, int n) {
    const int wave = threadIdx.x >> 6;
    const int lane = threadIdx.x & 63;
    const int node = blockIdx.x * 4 + wave;
    if (node >= n) return;
    const int e0 = rp[node], e1 = rp[node + 1];
    float a0 = 0.f, a1 = 0.f, a2 = 0.f, a3 = 0.f;
    int e = e0;
    for (; e + 7 < e1; e += 8) {
#pragma unroll
        for (int u = 0; u < 8; ++u) {
            int2 m = ew[e + u];
            float w = __int_as_float(m.y);
            char4 q = *(const char4*)(Q + (size_t)(uint)m.x + lane * 4);
            a0 += w * (float)q.x;
            a1 += w * (float)q.y;
            a2 += w * (float)q.z;
            a3 += w * (float)q.w;
        }
    }
    for (; e < e1; ++e) {
        int2 m = ew[e];
        float w = __int_as_float(m.y);
        char4 q = *(const char4*)(Q + (size_t)(uint)m.x + lane * 4);
        a0 += w * (float)q.x;
        a1 += w * (float)q.y;
        a2 += w * (float)q.z;
        a3 += w * (float)q.w;
    }
    float4 b = *(const float4*)(bias + lane * 4);
    ushort4 r;
    r.x = f2b(fmaxf(a0 + b.x, 0.f));
    r.y = f2b(fmaxf(a1 + b.y, 0.f));
    r.z = f2b(fmaxf(a2 + b.z, 0.f));
    r.w = f2b(fmaxf(a3 + b.w, 0.f));
    *(ushort4*)(H + (size_t)node * 256 + lane * 4) = r;
}

// ---------------------------------------------------------------------------
// SpMM layer2: out = sum_e w_e * Q2[c_e] + b2. Wave per node; lane = feature
// (1B gather/edge); ew.x pre-shifted (col*64); 16-edge unroll.
__global__ __launch_bounds__(256)
void spmm2_q(const char* __restrict__ Q, const int2* __restrict__ ew,
             const int* __restrict__ rp, const float* __restrict__ bias,
             float* __restrict__ O, int n) {
    const int wave = threadIdx.x >> 6;
    const int lane = threadIdx.x & 63;
    const int node = blockIdx.x * 4 + wave;
    if (node >= n) return;
    const int e0 = rp[node], e1 = rp[node + 1];
    float acc = 0.f;
    int e = e0;
    for (; e + 15 < e1; e += 16) {
#pragma unroll
        for (int u = 0; u < 16; ++u) {
            int2 m = ew[e + u];
            acc += __int_as_float(m.y) * (float)Q[(size_t)(uint)m.x + lane];
        }
    }
    for (; e + 3 < e1; e += 4) {
#pragma unroll
        for (int u = 0; u < 4; ++u) {
            int2 m = ew[e + u];
            acc += __int_as_float(m.y) * (float)Q[(size_t)(uint)m.x + lane];
        }
    }
    for (; e < e1; ++e) {
        int2 m = ew[e];
        acc += __int_as_float(m.y) * (float)Q[(size_t)(uint)m.x + lane];
    }
    O[(size_t)node * 64 + lane] = acc + bias[lane];
}

// ---------------------------------------------------------------------------
static inline size_t alignup(size_t x) { return (x + 255) & ~(size_t)255; }

extern "C" void kernel_launch(void* const* d_in, const int* in_sizes, int n_in,
                              void* d_out, int out_size, void* d_ws, size_t ws_size,
                              hipStream_t stream) {
    const float* X  = (const float*)d_in[0];
    const float* ev = (const float*)d_in[1];
    const float* W1 = (const float*)d_in[2];
    const float* b1 = (const float*)d_in[3];
    const float* W2 = (const float*)d_in[4];
    const float* b2 = (const float*)d_in[5];
    const int*  row = (const int*)d_in[6];
    const int*  col = (const int*)d_in[7];
    float* out = (float*)d_out;

    const int n = in_sizes[0] / IN_SIZE;   // 100000
    const int E = in_sizes[1];             // 3200000

    char* p = (char*)d_ws;
    ushort* H    = (ushort*)p; p += alignup((size_t)n * HID * 2);
    char*   Q1   = (char*)p;   p += alignup((size_t)n * HID);
    float*  s1   = (float*)p;  p += alignup((size_t)n * 4);
    char*   Q2   = (char*)p;   p += alignup((size_t)n * OUTF);
    float*  s2   = (float*)p;  p += alignup((size_t)n * 4);
    ushort* W1T  = (ushort*)p; p += alignup((size_t)IN_SIZE * HID * 2);
    ushort* W2T  = (ushort*)p; p += alignup((size_t)HID * OUTF * 2);
    int*    rp   = (int*)p;    p += alignup((size_t)(n + 1) * 4);
    int2*   ewb  = (int2*)p;   p += alignup((size_t)E * 8);

    const int rpB = (n + 1 + 255) / 256;
    setup_kernel<<<rpB + 256 + 64, 256, 0, stream>>>(row, rp, W1, W1T, W2, W2T,
                                                     n, E, rpB);

    // Q1,s1 = int8rowquant(bf16(X) @ W1)
    gemm1_q<<<(n + 127) / 128, 512, 0, stream>>>(X, W1T, Q1, s1, n);

    // ew = {col<<8, vals*s1[col]}
    prep_edges<<<(E + 255) / 256, 256, 0, stream>>>(ev, col, s1, ewb, E, 8);

    // H = relu(A @ deq(Q1) + b1)
    spmm1_q<<<(n + 3) / 4, 256, 0, stream>>>(Q1, ewb, rp, b1, H, n);

    // Q2,s2 = int8rowquant(H @ W2)
    gemm2_q<<<(n + 127) / 128, 256, 0, stream>>>(H, W2T, Q2, s2, n);

    // ew = {col<<6, vals*s2[col]}
    prep_edges<<<(E + 255) / 256, 256, 0, stream>>>(ev, col, s2, ewb, E, 6);

    // out = A @ deq(Q2) + b2
    spmm2_q<<<(n + 3) / 4, 256, 0, stream>>>(Q2, ewb, rp, b2, out, n);
}